// Round 2
// baseline (2121.493 us; speedup 1.0000x reference)
//
#include <hip/hip_runtime.h>

#define B_  8
#define LV_ 4096
#define D_  256
#define N_  2048
#define P_  32
#define BPW 4                       // bins per wave (4 independent load chains)
#define SLOTS_PER_XCD (N_ / B_)     // 256 boxes per XCD share

// Pass 1: counting-sort box indices by batch into order[] (d_ws).
// Per-batch feat slice = LV*D*4 = 4 MiB = exactly one XCD's L2.
__global__ __launch_bounds__(256) void build_order_kernel(
    const int* __restrict__ batch_idx, int* __restrict__ order)
{
    __shared__ int cnt[B_];
    __shared__ int off[B_];
    const int tid = threadIdx.x;
    if (tid < B_) cnt[tid] = 0;
    __syncthreads();
    for (int n = tid; n < N_; n += 256)
        atomicAdd(&cnt[batch_idx[n]], 1);
    __syncthreads();
    if (tid == 0) {
        int s = 0;
        for (int b = 0; b < B_; ++b) { off[b] = s; s += cnt[b]; }
    }
    __syncthreads();
    for (int n = tid; n < N_; n += 256) {
        const int b   = batch_idx[n];
        const int pos = atomicAdd(&off[b], 1);   // off doubles as cursor
        order[pos] = n;
    }
}

// Pass 2: one wave per (box, 4 consecutive bins). blockIdx mapping routes
// slot range [256*x, 256*x+256) (≈ batch x after the sort) to XCD x = i%8,
// so each XCD's L2 holds its batch's 4 MiB slice resident.
__global__ __launch_bounds__(64) void roi_align1d_kernel(
    const float* __restrict__ feat,       // [B, LV, D]
    const float* __restrict__ boxes,      // [N, 2]
    const int*   __restrict__ batch_idx,  // [N]
    const int*   __restrict__ order,      // [N] sorted-by-batch box ids
    float*       __restrict__ out)        // [N, P, D]
{
    const int i    = blockIdx.x;          // 16384 blocks
    const int xcd  = i & 7;
    const int r    = i >> 3;              // 0..2047, increasing per-XCD over time
    const int slot = xcd * SLOTS_PER_XCD + (r >> 3);
    const int p0   = (r & 7) * BPW;
    const int lane = threadIdx.x;

    const int n = order[slot];

    const float y1    = boxes[2 * n];
    const float y2    = boxes[2 * n + 1];
    const float bin_h = (y2 - y1) * (1.0f / (float)P_);
    const int   gh    = (int)ceilf(bin_h);
    const int   cnt   = gh > 1 ? gh : 1;
    const float sub   = bin_h / (float)cnt;
    const float inv_c = 1.0f / (float)cnt;

    const float4* frow = (const float4*)feat + (long)batch_idx[n] * LV_ * 64 + lane;

    float  boff[BPW];
    float4 acc[BPW], vlo[BPW], vhi[BPW];
    int    cur[BPW];
    #pragma unroll
    for (int j = 0; j < BPW; ++j) {
        boff[j] = (y1 - 0.5f) + (float)(p0 + j) * bin_h;
        acc[j]  = make_float4(0.f, 0.f, 0.f, 0.f);
        vlo[j]  = vhi[j] = acc[j];
        cur[j]  = -100;
    }

    for (int g = 0; g < gh; ++g) {
        const float gc = (float)g + 0.5f;
        #pragma unroll
        for (int j = 0; j < BPW; ++j) {
            const float y  = boff[j] + gc * sub;
            const float yc = fmaxf(y, 0.0f);
            int   lo = (int)floorf(yc);
            int   hi;
            float ly;
            if (lo >= LV_ - 1) { lo = LV_ - 1; hi = LV_ - 1; ly = 0.0f; }
            else               { hi = lo + 1;  ly = yc - (float)lo; }
            const bool  valid = (y >= -1.0f) && (y <= (float)LV_);
            const float w1 = valid ? ly : 0.0f;
            const float w0 = valid ? (1.0f - ly) : 0.0f;

            if (lo != cur[j]) {            // wave-uniform per-bin row walk
                vlo[j] = (lo == cur[j] + 1) ? vhi[j] : frow[lo * 64];
                vhi[j] = (hi != lo) ? frow[hi * 64] : vlo[j];
                cur[j] = lo;
            }

            acc[j].x = fmaf(w0, vlo[j].x, acc[j].x);
            acc[j].y = fmaf(w0, vlo[j].y, acc[j].y);
            acc[j].z = fmaf(w0, vlo[j].z, acc[j].z);
            acc[j].w = fmaf(w0, vlo[j].w, acc[j].w);
            acc[j].x = fmaf(w1, vhi[j].x, acc[j].x);
            acc[j].y = fmaf(w1, vhi[j].y, acc[j].y);
            acc[j].z = fmaf(w1, vhi[j].z, acc[j].z);
            acc[j].w = fmaf(w1, vhi[j].w, acc[j].w);
        }
    }

    #pragma unroll
    for (int j = 0; j < BPW; ++j) {
        float4 v;
        v.x = acc[j].x * inv_c;
        v.y = acc[j].y * inv_c;
        v.z = acc[j].z * inv_c;
        v.w = acc[j].w * inv_c;
        ((float4*)out)[((long)n * P_ + p0 + j) * 64 + lane] = v;  // 4KB contig/wave
    }
}

extern "C" void kernel_launch(void* const* d_in, const int* in_sizes, int n_in,
                              void* d_out, int out_size, void* d_ws, size_t ws_size,
                              hipStream_t stream) {
    const float* feat      = (const float*)d_in[0];
    const float* boxes     = (const float*)d_in[1];
    const int*   batch_idx = (const int*)d_in[2];
    float*       out       = (float*)d_out;
    int*         order     = (int*)d_ws;    // N_ ints

    build_order_kernel<<<1, 256, 0, stream>>>(batch_idx, order);
    roi_align1d_kernel<<<N_ * P_ / BPW, 64, 0, stream>>>(feat, boxes, batch_idx, order, out);
}

// Round 3
// 684.123 us; speedup vs baseline: 3.1010x; 3.1010x over previous
//
#include <hip/hip_runtime.h>

#define B_   8
#define LV_  4096
#define D_   256
#define N_   2048
#define P_   32
#define T_   64               // rows per tile
#define NT_  (LV_ / T_)       // 64 tiles per batch image
#define WGT_ 512              // threads per workgroup (8 waves)
#define NWAVE (WGT_ / 64)

// Pass 1: counting-sort box ids by batch; order[N] + exclusive offsets off0[B+1].
__global__ __launch_bounds__(256) void build_order_kernel(
    const int* __restrict__ batch_idx, int* __restrict__ order, int* __restrict__ off0)
{
    __shared__ int cnt[B_];
    __shared__ int cur[B_];
    const int tid = threadIdx.x;
    if (tid < B_) cnt[tid] = 0;
    __syncthreads();
    for (int n = tid; n < N_; n += 256) atomicAdd(&cnt[batch_idx[n]], 1);
    __syncthreads();
    if (tid == 0) {
        int s = 0;
        for (int b = 0; b < B_; ++b) { cur[b] = s; off0[b] = s; s += cnt[b]; }
        off0[B_] = s;
    }
    __syncthreads();
    for (int n = tid; n < N_; n += 256) {
        const int b = batch_idx[n];
        order[atomicAdd(&cur[b], 1)] = n;
    }
}

// Pass 2: one WG per (batch b, 64-row tile t). Stage rows [r0, r0+64) into LDS
// once; process every sample s of every box of batch b whose lo-row falls in
// the tile (samples are a uniform grid, so the owned s-range is an interval).
// Complete-in-tile bins -> plain store; straddling bins -> atomicAdd on zeroed out.
__global__ __launch_bounds__(WGT_) void roi_tile_kernel(
    const float* __restrict__ feat,     // [B, LV, D]
    const float* __restrict__ boxes,    // [N, 2]
    const int*   __restrict__ order,    // [N] sorted by batch
    const int*   __restrict__ off0,     // [B+1]
    float*       __restrict__ out)      // [N, P, D], pre-zeroed
{
    __shared__ float lds[T_ * D_];      // 64 KB -> 2 WGs/CU
    const int wg   = blockIdx.x;        // 0..511
    const int b    = wg >> 6;
    const int t    = wg & (NT_ - 1);
    const int r0   = t * T_;
    const int tid  = threadIdx.x;
    const int lane = tid & 63;
    const int wv   = tid >> 6;

    // ---- stage tile (coalesced float4) ----
    {
        const float4* src = (const float4*)feat + ((long)b * LV_ + r0) * (D_ / 4);
        float4* dst = (float4*)lds;
        #pragma unroll
        for (int i = 0; i < T_ * (D_ / 4) / WGT_; ++i)
            dst[tid + i * WGT_] = src[tid + i * WGT_];
    }
    __syncthreads();

    const int beg = off0[b], end = off0[b + 1];
    const float4* fbase = (const float4*)feat + (long)b * LV_ * (D_ / 4) + lane; // + row*64
    const float4* lrow  = (const float4*)lds + lane;                             // + row*64

    for (int bi = beg + wv; bi < end; bi += NWAVE) {
        const int   n  = order[bi];
        const float y1 = boxes[2 * n];
        const float y2 = boxes[2 * n + 1];
        // cheap conservative prefilter
        if (y2 + 1.0f < (float)r0 || y1 - 1.0f > (float)(r0 + T_)) continue;

        const float bin_h = (y2 - y1) * (1.0f / (float)P_);
        const int   gh    = (int)ceilf(bin_h);
        if (gh < 1) continue;                    // ref output 0; memset covers it
        const int   cntk  = gh;
        const float sub   = bin_h / (float)cntk;
        const float inv_c = 1.0f / (float)cntk;
        const float start = y1 - 0.5f;
        const int   K     = P_ * cntk;

        // lo_c(s): clamped lo row of sample s, same fp32 expr as the value loop
        auto lo_c = [&](int s) -> int {
            const int   p = s / cntk;
            const int   g = s - p * cntk;
            const float y = fmaf((float)g + 0.5f, sub, fmaf((float)p, bin_h, start));
            const int  lo = (int)floorf(fmaxf(y, 0.0f));
            return lo < LV_ - 1 ? lo : LV_ - 1;
        };
        // min s in [0,K] with lo_c(s) >= R  (lo_c monotone nondecreasing in s)
        auto lower_bound = [&](int R) -> int {
            double s0d = ((double)R - (double)start) / (double)sub - 0.5;
            int s0 = (int)fmax(0.0, fmin((double)K, s0d));
            while (s0 > 0 && lo_c(s0 - 1) >= R) --s0;
            while (s0 < K && lo_c(s0) < R) ++s0;
            return s0;
        };
        const int s_begin = lower_bound(r0);
        const int s_end   = lower_bound(r0 + T_);
        if (s_begin >= s_end) continue;

        int   p = s_begin / cntk;
        int   g = s_begin - p * cntk;
        bool  first_owned = (g == 0);
        float base_p = fmaf((float)p, bin_h, start);
        float4 acc = make_float4(0.f, 0.f, 0.f, 0.f);
        float4 vlo = acc, vhi = acc;
        int   cur_lo = -1000;

        for (int s = s_begin; s < s_end; ++s, ++g) {
            const float y  = fmaf((float)g + 0.5f, sub, base_p);
            const float yc = fmaxf(y, 0.0f);
            int   lo = (int)floorf(yc);
            int   hi;
            float ly;
            if (lo >= LV_ - 1) { lo = LV_ - 1; hi = lo; ly = 0.0f; }
            else               { hi = lo + 1;  ly = yc - (float)lo; }
            const bool  valid = (y >= -1.0f) && (y <= (float)LV_);
            const float w1 = valid ? ly : 0.0f;
            const float w0 = valid ? (1.0f - ly) : 0.0f;

            if (lo != cur_lo) {                  // wave-uniform row walk (lo steps by <=1)
                vlo = (lo == cur_lo + 1) ? vhi : lrow[(lo - r0) * (D_ / 4)];
                if (hi == lo)               vhi = vlo;
                else if (hi - r0 < T_)      vhi = lrow[(hi - r0) * (D_ / 4)];
                else                        vhi = fbase[(long)hi * (D_ / 4)]; // halo row via L2
                cur_lo = lo;
            }

            acc.x = fmaf(w0, vlo.x, acc.x);
            acc.y = fmaf(w0, vlo.y, acc.y);
            acc.z = fmaf(w0, vlo.z, acc.z);
            acc.w = fmaf(w0, vlo.w, acc.w);
            acc.x = fmaf(w1, vhi.x, acc.x);
            acc.y = fmaf(w1, vhi.y, acc.y);
            acc.z = fmaf(w1, vhi.z, acc.z);
            acc.w = fmaf(w1, vhi.w, acc.w);

            if (g + 1 == cntk || s + 1 == s_end) {   // flush bin p
                const bool complete = first_owned && (g + 1 == cntk);
                float4 v;
                v.x = acc.x * inv_c; v.y = acc.y * inv_c;
                v.z = acc.z * inv_c; v.w = acc.w * inv_c;
                float* op = out + ((long)n * P_ + p) * D_ + 4 * lane;
                if (complete) {
                    *(float4*)op = v;
                } else {
                    atomicAdd(op + 0, v.x);
                    atomicAdd(op + 1, v.y);
                    atomicAdd(op + 2, v.z);
                    atomicAdd(op + 3, v.w);
                }
                ++p; g = -1;
                base_p = fmaf((float)p, bin_h, start);
                acc = make_float4(0.f, 0.f, 0.f, 0.f);
                first_owned = true;
            }
        }
    }
}

extern "C" void kernel_launch(void* const* d_in, const int* in_sizes, int n_in,
                              void* d_out, int out_size, void* d_ws, size_t ws_size,
                              hipStream_t stream) {
    const float* feat      = (const float*)d_in[0];
    const float* boxes     = (const float*)d_in[1];
    const int*   batch_idx = (const int*)d_in[2];
    float*       out       = (float*)d_out;
    int*         order     = (int*)d_ws;          // N_ ints
    int*         off0      = order + N_;          // B_+1 ints

    hipMemsetAsync(out, 0, (size_t)out_size * sizeof(float), stream);
    build_order_kernel<<<1, 256, 0, stream>>>(batch_idx, order, off0);
    roi_tile_kernel<<<B_ * NT_, WGT_, 0, stream>>>(feat, boxes, order, off0, out);
}